// Round 14
// baseline (502.227 us; speedup 1.0000x reference)
//
#include <hip/hip_runtime.h>

#define HH 50
#define TT 1024
#define BT 4             // batch tile per block (quarter of MFMA M)
#define NB (2048 / BT)   // 512 blocks -> 2 per CU (cross-block latency hiding)
#define HST 72           // h row stride in shorts (144B; natural bank rotation)
#define HBUF (16 * HST)  // shorts per h buffer

typedef _Float16 half8 __attribute__((ext_vector_type(8)));
typedef float f32x4 __attribute__((ext_vector_type(4)));

union H8 { half8 v; _Float16 h[8]; unsigned short u[8]; unsigned int i[4]; };

__device__ __forceinline__ float rcp_f(float x) { return __builtin_amdgcn_rcpf(x); }

#if __has_builtin(__builtin_amdgcn_exp2f)
__device__ __forceinline__ float exp2_f(float x) { return __builtin_amdgcn_exp2f(x); }
#else
__device__ __forceinline__ float exp2_f(float x) { return __expf(0.6931471805599453f * x); }
#endif

#define L2E   1.4426950408889634f
#define L2E2  2.8853900817779268f

__device__ __forceinline__ float sigm_n(float a) {   // sigmoid(x), a = -x*log2e
    return rcp_f(1.0f + exp2_f(a));
}
__device__ __forceinline__ float tanh_p(float a) {   // tanh(x), a = 2x*log2e
    return __builtin_fmaf(-2.0f, rcp_f(1.0f + exp2_f(a)), 1.0f);
}
__device__ __forceinline__ unsigned short f2h(float f) {
    return __builtin_bit_cast(unsigned short, (_Float16)f);
}

__global__ __launch_bounds__(256) void lstm_mfma_kernel(
    const float* __restrict__ x,
    const float* __restrict__ wih1, const float* __restrict__ whh1,
    const float* __restrict__ bih1, const float* __restrict__ bhh1,
    const float* __restrict__ wih2,
    const float* __restrict__ bih2, const float* __restrict__ bhh2,
    const float* __restrict__ fcw,  const float* __restrict__ fcb,
    float* __restrict__ out)
{
    __shared__ __align__(16) unsigned short hb[2][HBUF];   // 4.6 KB (linear, r10-proven)
    __shared__ unsigned short xh[(TT + 2) * BT];           // 8.2 KB f16 x, [t][b]
    __shared__ float h2s[BT * 52];                         // 0.8 KB   (total ~13.7 KB)

    const int tid  = threadIdx.x;
    const int wv   = tid >> 6;        // 0..3 = j-slice
    const int js   = wv;
    const int lane = tid & 63;
    const int l16  = lane & 15;
    const int quad = lane >> 4;
    const int j    = js * 16 + l16;   // padded gate sub-index 0..63
    const bool jv  = (j < HH);
    const bool q2  = (quad == 2);
    const int b0   = blockIdx.x * BT;
    // 1 cell/lane: lane (quad,l16) owns (batch=quad, j).  Valid D rows 0..3
    // live in quad-0 regs 0..3; fan-out via permlane tree (r9-verified):
    //   xx0=acc[0],xx1=acc[1],yy0=acc[2],yy1=acc[3];
    //   p16swap(xx0,xx1); p16swap(yy0,yy1); p32swap(xx0,yy0); P = xx0.

    // ---- persistent per-lane weights: Whh B-frags (f16, gate-folded scale) ----
    // K layout: k=0..49 Whh; k=50 <- Wih (x slot); k=51 <- bias_hi; k=52 <- bias_lo
    H8 bw[4][2];
    #pragma unroll
    for (int t4 = 0; t4 < 4; ++t4) {
        const float sc = (t4 == 2) ? L2E2 : -L2E;
        const int row = t4 * HH + j;
        #pragma unroll
        for (int kk = 0; kk < 2; ++kk)
            #pragma unroll
            for (int e = 0; e < 8; ++e) {
                const int k = kk * 32 + quad * 8 + e;
                const float v = (jv && k < HH) ? whh1[row * HH + k] * sc : 0.0f;
                bw[t4][kk].h[e] = (_Float16)v;
            }
        if (q2) {
            const float bsc = jv ? (bih1[row] + bhh1[row]) * sc : 0.0f;
            const _Float16 bhi = (_Float16)bsc;
            bw[t4][1].h[2] = (_Float16)(jv ? wih1[row] * sc : 0.0f); // k=50
            bw[t4][1].h[3] = bhi;                                    // k=51
            bw[t4][1].h[4] = (_Float16)(bsc - (float)bhi);           // k=52
        }
    }

    // ---- init h buffers: zero with 1.0 planted at cols 51,52 (single pass) ----
    for (int i = tid; i < 2 * HBUF; i += 256) {
        const int col = i % HST;
        ((unsigned short*)hb)[i] = (col == 51 || col == 52) ? 0x3c00 : 0;
    }

    // ---- stage x as f16 into xh[t][b] (one-time conversion; 4 float4/thread) ----
    for (int i = tid; i < BT * (TT / 4); i += 256) {
        const int r = i >> 8, c4 = i & 255;
        const float4 q = ((const float4*)x)[((b0 + r) * TT) / 4 + c4];
        const int t0 = c4 * 4;
        xh[(t0 + 0) * BT + r] = f2h(q.x);
        xh[(t0 + 1) * BT + r] = f2h(q.y);
        xh[(t0 + 2) * BT + r] = f2h(q.z);
        xh[(t0 + 3) * BT + r] = f2h(q.w);
    }
    if (tid < 2 * BT) xh[TT * BT + tid] = 0;   // pad t=1024,1025 (last prefetch)
    __syncthreads();

    // x(0) into the k=50 slot of buffer 0, rows 0..3
    if (wv == 0 && lane < BT) hb[0][lane * HST + 50] = xh[lane];
    __syncthreads();

    // ---- hoisted per-lane addresses (constant across the whole loop) ----
    const int ra0 = l16 * HST + quad * 8;        // A-frag K-half 0
    const int ra1 = ra0 + 32;                    // A-frag K-half 1
    // h write: invalid-j lanes redirect to dump rows 4..7 (never consumed:
    // garbage rows only feed D rows >=4, which are discarded everywhere)
    const int r0  = jv ? quad : (4 + quad);
    const int wa0 = r0 * HST + j;
    // x relay: wave0 lanes 0..3 hit the real slot; others hit dump rows 8..11
    const int xrow = (wv == 0 && lane < BT) ? lane : (8 + (lane & 3));
    const int wx   = xrow * HST + 50;
    const int xsub = lane & 3;                   // broadcast-read lane for xh

    float c0 = 0.f;
    const f32x4 kZ = {0.f, 0.f, 0.f, 0.f};

    // fused cell: 7 trans (5 exp2 + 2 rcp)
    auto cell = [&](float ai, float af, float ag, float ao, float& cc) -> unsigned short {
        const float Ei = exp2_f(ai), Ef = exp2_f(af), Eg = exp2_f(ag), Eo = exp2_f(ao);
        const float pf  = 1.0f + Ef;
        const float P   = (1.0f + Ei) * (1.0f + Eg);
        const float den = pf * P;
        const float num = __builtin_fmaf(cc, P, (Eg - 1.0f) * pf);
        cc = num * rcp_f(den);
        const float ac = fminf(cc * L2E2, 80.0f);
        const float Ec = exp2_f(ac);
        const float h  = (Ec - 1.0f) * rcp_f((1.0f + Eo) * (1.0f + Ec));
        return f2h(h);
    };

    // fan-out acc[G][quad] (quad0 regs) -> lane (quad,l16)  [r9-verified]
#define REDIST(G, PG)                                                          \
    {                                                                          \
        float xx0 = acc[G][0], xx1 = acc[G][1];                                \
        float yy0 = acc[G][2], yy1 = acc[G][3];                                \
        asm("v_permlane16_swap_b32 %0, %1" : "+v"(xx0), "+v"(xx1));            \
        asm("v_permlane16_swap_b32 %0, %1" : "+v"(yy0), "+v"(yy1));            \
        asm("v_permlane32_swap_b32 %0, %1" : "+v"(xx0), "+v"(yy0));            \
        PG = xx0;                                                              \
    }

#define STEP(T, CB, NBUF)                                                      \
    {                                                                          \
        H8 a0, a1;                                                             \
        a0.v = *(const half8*)&hb[CB][ra0];                                    \
        a1.v = *(const half8*)&hb[CB][ra1];                                    \
        /* xn read after a0/a1; carried in a register, written at step tail    \
           (r12 lesson: writing here would inject LDS latency into the chain) */\
        const unsigned short xn = xh[((T) + 1) * BT + xsub];                   \
        f32x4 acc[4];                                                          \
        _Pragma("unroll")                                                      \
        for (int t4 = 0; t4 < 4; ++t4) {                                       \
            acc[t4] = __builtin_amdgcn_mfma_f32_16x16x32_f16(a0.v, bw[t4][0].v, kZ, 0, 0, 0);       \
            acc[t4] = __builtin_amdgcn_mfma_f32_16x16x32_f16(a1.v, bw[t4][1].v, acc[t4], 0, 0, 0);  \
        }                                                                      \
        float p0, p1, p2, p3;                                                  \
        REDIST(0, p0) REDIST(1, p1) REDIST(2, p2) REDIST(3, p3)                \
        const unsigned short h0 = cell(p0, p1, p2, p3, c0);                    \
        hb[NBUF][wa0] = h0;                                                    \
        hb[NBUF][wx]  = xn;                                                    \
        __syncthreads();                                                       \
    }

    for (int t = 0; t < TT; t += 2) {
        STEP(t,     0, 1);
        STEP(t + 1, 1, 0);
    }
#undef STEP
#undef REDIST
    // final h1 in hb[0] rows 0..3 (rows 4..15 = bounded/garbage, never consumed)

    // ---- LSTM2: one cell step from zero state, input = h1 ----
    {
        H8 bw2[4][2];
        float b2[4];
        #pragma unroll
        for (int t4 = 0; t4 < 4; ++t4) {
            const float sc = (t4 == 2) ? L2E2 : -L2E;
            const int row = t4 * HH + j;
            #pragma unroll
            for (int kk = 0; kk < 2; ++kk)
                #pragma unroll
                for (int e = 0; e < 8; ++e) {
                    const int k = kk * 32 + quad * 8 + e;
                    const float v = (jv && k < HH) ? wih2[row * HH + k] * sc : 0.0f;
                    bw2[t4][kk].h[e] = (_Float16)v;
                }
            b2[t4] = jv ? (bih2[row] + bhh2[row]) * sc : 0.0f;
        }
        // garbage batch-rows 4-15 feed only D rows 4-15 (discarded by b<BT);
        // k=50 slot holds x(1024)=0 pad, k=51/52 hold 1.0 -> meet bw2=0 there.
        H8 a0, a1;
        a0.v = *(const half8*)&hb[0][ra0];
        a1.v = *(const half8*)&hb[0][ra1];
        f32x4 acc2[4];
        #pragma unroll
        for (int t4 = 0; t4 < 4; ++t4) {
            const f32x4 cb = {b2[t4], b2[t4], b2[t4], b2[t4]};
            acc2[t4] = __builtin_amdgcn_mfma_f32_16x16x32_f16(a0.v, bw2[t4][0].v, cb, 0, 0, 0);
            acc2[t4] = __builtin_amdgcn_mfma_f32_16x16x32_f16(a1.v, bw2[t4][1].v, acc2[t4], 0, 0, 0);
        }
        #pragma unroll
        for (int r = 0; r < 4; ++r) {
            const int b = quad * 4 + r;          // valid rows 0..3 (quad 0)
            const float ig = sigm_n(acc2[0][r]);
            const float gg = tanh_p(acc2[2][r]);
            const float og = sigm_n(acc2[3][r]);
            const float cc = ig * gg;            // f*c0 term vanishes (c0 = 0)
            const float h2 = og * tanh_p(cc * L2E2);
            if (b < BT && jv) h2s[b * 52 + j] = h2;
        }
    }
    __syncthreads();

    // ---- FC: out[b] = h2[b] . fcW + fcb  (4 batches x 16 lanes) ----
    if (tid < BT * 16) {
        const int b = tid >> 4, l = tid & 15;
        float p = 0.f;
        for (int jj = l; jj < HH; jj += 16)
            p = __builtin_fmaf(h2s[b * 52 + jj], fcw[jj], p);
        #pragma unroll
        for (int off = 8; off > 0; off >>= 1) p += __shfl_xor(p, off, 16);
        if (l == 0) out[b0 + b] = p + fcb[0];
    }
}

extern "C" void kernel_launch(void* const* d_in, const int* in_sizes, int n_in,
                              void* d_out, int out_size, void* d_ws, size_t ws_size,
                              hipStream_t stream) {
    lstm_mfma_kernel<<<NB, 256, 0, stream>>>(
        (const float*)d_in[0],                         // x
        (const float*)d_in[1], (const float*)d_in[2],  // lstm1 Wih, Whh
        (const float*)d_in[3], (const float*)d_in[4],  // lstm1 bih, bhh
        (const float*)d_in[5],                         // lstm2 Wih
        (const float*)d_in[7], (const float*)d_in[8],  // lstm2 bih, bhh
        (const float*)d_in[9], (const float*)d_in[10], // fc W, b
        (float*)d_out);
}

// Round 15
// 430.405 us; speedup vs baseline: 1.1669x; 1.1669x over previous
//
#include <hip/hip_runtime.h>

#define HH 50
#define TT 1024
#define BT 8             // batch tile per block
#define NB (2048 / BT)   // 256 blocks -> 1 per CU
#define HST 72           // h row stride in shorts (144B; natural bank rotation)
#define HBUF (16 * HST)  // shorts per h buffer

typedef _Float16 half8 __attribute__((ext_vector_type(8)));
typedef float f32x4 __attribute__((ext_vector_type(4)));

union H8 { half8 v; _Float16 h[8]; unsigned short u[8]; unsigned int i[4]; };

__device__ __forceinline__ float rcp_f(float x) { return __builtin_amdgcn_rcpf(x); }

#if __has_builtin(__builtin_amdgcn_exp2f)
__device__ __forceinline__ float exp2_f(float x) { return __builtin_amdgcn_exp2f(x); }
#else
__device__ __forceinline__ float exp2_f(float x) { return __expf(0.6931471805599453f * x); }
#endif

#define L2E   1.4426950408889634f
#define L2E2  2.8853900817779268f

__device__ __forceinline__ float sigm_n(float a) {   // sigmoid(x), a = -x*log2e
    return rcp_f(1.0f + exp2_f(a));
}
__device__ __forceinline__ float tanh_p(float a) {   // tanh(x), a = 2x*log2e
    return __builtin_fmaf(-2.0f, rcp_f(1.0f + exp2_f(a)), 1.0f);
}
__device__ __forceinline__ unsigned short f2h(float f) {
    return __builtin_bit_cast(unsigned short, (_Float16)f);
}

__global__ __launch_bounds__(256) void lstm_mfma_kernel(
    const float* __restrict__ x,
    const float* __restrict__ wih1, const float* __restrict__ whh1,
    const float* __restrict__ bih1, const float* __restrict__ bhh1,
    const float* __restrict__ wih2,
    const float* __restrict__ bih2, const float* __restrict__ bhh2,
    const float* __restrict__ fcw,  const float* __restrict__ fcb,
    float* __restrict__ out)
{
    __shared__ __align__(16) unsigned short hb[2][HBUF];   // 4.6 KB (linear, r10-proven)
    __shared__ unsigned short xh[(TT + 2) * BT];           // 16.1 KB f16 x, [t][b]
    __shared__ float h2s[BT * 52];                         // 1.7 KB

    const int tid  = threadIdx.x;
    const int wv   = tid >> 6;        // 0..3 = j-slice
    const int js   = wv;
    const int lane = tid & 63;
    const int l16  = lane & 15;
    const int quad = lane >> 4;
    const int j    = js * 16 + l16;   // padded gate sub-index 0..63
    const bool jv  = (j < HH);
    const bool q2  = (quad == 2);
    const int b0   = blockIdx.x * BT;
    // ownership (r10 mapping, verified): lane (quad,l16) owns batches bm0, bm0+1,
    // bm0 = q0:0, q1:4, q2:2, q3:6; redistribution via v_permlane32_swap
    // (vdst.lo kept, vdst.hi <- vsrc.lo).
    const int bm0 = ((quad & 1) << 2) + ((quad >> 1) << 1);

    // ---- persistent per-lane weights: Whh B-frags (f16, gate-folded scale) ----
    // K layout: k=0..49 Whh; k=50 <- Wih (x slot); k=51 <- bias_hi; k=52 <- bias_lo
    H8 bw[4][2];
    #pragma unroll
    for (int t4 = 0; t4 < 4; ++t4) {
        const float sc = (t4 == 2) ? L2E2 : -L2E;
        const int row = t4 * HH + j;
        #pragma unroll
        for (int kk = 0; kk < 2; ++kk)
            #pragma unroll
            for (int e = 0; e < 8; ++e) {
                const int k = kk * 32 + quad * 8 + e;
                const float v = (jv && k < HH) ? whh1[row * HH + k] * sc : 0.0f;
                bw[t4][kk].h[e] = (_Float16)v;
            }
        if (q2) {
            const float bsc = jv ? (bih1[row] + bhh1[row]) * sc : 0.0f;
            const _Float16 bhi = (_Float16)bsc;
            bw[t4][1].h[2] = (_Float16)(jv ? wih1[row] * sc : 0.0f); // k=50
            bw[t4][1].h[3] = bhi;                                    // k=51
            bw[t4][1].h[4] = (_Float16)(bsc - (float)bhi);           // k=52
        }
    }

    // ---- init h buffers: zero with 1.0 planted at cols 51,52 (single pass) ----
    // cols 51,52 are never rewritten (h writes cover j<50, x relay col 50 only),
    // rows 8..15 are never written -> stay zero.
    for (int i = tid; i < 2 * HBUF; i += 256) {
        const int col = i % HST;
        ((unsigned short*)hb)[i] = (col == 51 || col == 52) ? 0x3c00 : 0;
    }

    // ---- stage x as f16 into xh[t][b] (one-time conversion) ----
    for (int i = tid; i < BT * (TT / 4); i += 256) {
        const int r = i >> 8, c4 = i & 255;
        const float4 q = ((const float4*)x)[((b0 + r) * TT) / 4 + c4];
        const int t0 = c4 * 4;
        xh[(t0 + 0) * BT + r] = f2h(q.x);
        xh[(t0 + 1) * BT + r] = f2h(q.y);
        xh[(t0 + 2) * BT + r] = f2h(q.z);
        xh[(t0 + 3) * BT + r] = f2h(q.w);
    }
    if (tid < 2 * BT) xh[TT * BT + tid] = 0;   // pad t=1024,1025 (last prefetch)
    __syncthreads();

    // x(0) into the k=50 slot of buffer 0, rows 0..7
    const bool xw = (wv == 0) && (lane < BT);   // x-relay lanes (row = lane)
    if (xw) hb[0][lane * HST + 50] = xh[lane];
    __syncthreads();

    // ---- hoisted per-lane addresses ----
    const int ra0 = l16 * HST + quad * 8;        // A-frag K-half 0
    const int ra1 = ra0 + 32;                    // A-frag K-half 1
    const int wa0 = bm0 * HST + j;               // h write row bm0 (jv-masked)
    const int wa1 = wa0 + HST;                   // h write row bm0+1
    const int wx  = lane * HST + 50;             // x relay (xw-masked)

    float c0 = 0.f, c1 = 0.f;
    const f32x4 kZ = {0.f, 0.f, 0.f, 0.f};

    // fused cell: 7 trans (5 exp2 + 2 rcp)
    auto cell = [&](float ai, float af, float ag, float ao, float& cc) -> unsigned short {
        const float Ei = exp2_f(ai), Ef = exp2_f(af), Eg = exp2_f(ag), Eo = exp2_f(ao);
        const float pf  = 1.0f + Ef;
        const float P   = (1.0f + Ei) * (1.0f + Eg);
        const float den = pf * P;
        const float num = __builtin_fmaf(cc, P, (Eg - 1.0f) * pf);
        cc = num * rcp_f(den);
        const float ac = fminf(cc * L2E2, 80.0f);
        const float Ec = exp2_f(ac);
        const float h  = (Ec - 1.0f) * rcp_f((1.0f + Eo) * (1.0f + Ec));
        return f2h(h);
    };

#define REDIST(G, P0, P1)                                                      \
    {                                                                          \
        float a_ = acc[G][0], b_ = acc[G][1];                                  \
        float c_ = acc[G][2], d_ = acc[G][3];                                  \
        asm("v_permlane32_swap_b32 %0, %1" : "+v"(a_), "+v"(c_));              \
        asm("v_permlane32_swap_b32 %0, %1" : "+v"(b_), "+v"(d_));              \
        P0 = a_;                                                               \
        P1 = b_;                                                               \
    }

#define STEP(T, CB, NBUF)                                                      \
    {                                                                          \
        H8 a0, a1;                                                             \
        a0.v = *(const half8*)&hb[CB][ra0];                                    \
        a1.v = *(const half8*)&hb[CB][ra1];                                    \
        /* x relay: read after a0/a1, carry in a register, write at tail       \
           (r12 lesson: an early LDS write injects read latency into chain) */ \
        unsigned short xn = 0;                                                 \
        if (xw) xn = xh[((T) + 1) * BT + lane];                                \
        f32x4 acc[4];                                                          \
        _Pragma("unroll")                                                      \
        for (int t4 = 0; t4 < 4; ++t4) {                                       \
            acc[t4] = __builtin_amdgcn_mfma_f32_16x16x32_f16(a0.v, bw[t4][0].v, kZ, 0, 0, 0);       \
            acc[t4] = __builtin_amdgcn_mfma_f32_16x16x32_f16(a1.v, bw[t4][1].v, acc[t4], 0, 0, 0);  \
        }                                                                      \
        float pi0, pi1, pf0, pf1, pg0, pg1, po0, po1;                          \
        REDIST(0, pi0, pi1) REDIST(1, pf0, pf1)                                \
        REDIST(2, pg0, pg1) REDIST(3, po0, po1)                                \
        const unsigned short h0 = cell(pi0, pf0, pg0, po0, c0);                \
        const unsigned short h1 = cell(pi1, pf1, pg1, po1, c1);                \
        if (jv) {   /* j>=50 lanes must not clobber the planted k-slots */     \
            hb[NBUF][wa0] = h0;                                                \
            hb[NBUF][wa1] = h1;                                                \
        }                                                                      \
        if (xw) hb[NBUF][wx] = xn;                                             \
        __syncthreads();                                                       \
    }

    for (int t = 0; t < TT; t += 2) {
        STEP(t,     0, 1);
        STEP(t + 1, 1, 0);
    }
#undef STEP
#undef REDIST
    // final h1 in hb[0] rows 0..7 (rows 8..15 zero; k=50 holds x(1024)=0 pad)

    // ---- LSTM2: one cell step from zero state, input = h1 ----
    {
        H8 bw2[4][2];
        float b2[4];
        #pragma unroll
        for (int t4 = 0; t4 < 4; ++t4) {
            const float sc = (t4 == 2) ? L2E2 : -L2E;
            const int row = t4 * HH + j;
            #pragma unroll
            for (int kk = 0; kk < 2; ++kk)
                #pragma unroll
                for (int e = 0; e < 8; ++e) {
                    const int k = kk * 32 + quad * 8 + e;
                    const float v = (jv && k < HH) ? wih2[row * HH + k] * sc : 0.0f;
                    bw2[t4][kk].h[e] = (_Float16)v;
                }
            b2[t4] = jv ? (bih2[row] + bhh2[row]) * sc : 0.0f;
        }
        // rows 8-15 zero; k=50 slot = 0, k=51/52 = 1.0 -> all meet bw2=0 there.
        H8 a0, a1;
        a0.v = *(const half8*)&hb[0][ra0];
        a1.v = *(const half8*)&hb[0][ra1];
        f32x4 acc2[4];
        #pragma unroll
        for (int t4 = 0; t4 < 4; ++t4) {
            const f32x4 cb = {b2[t4], b2[t4], b2[t4], b2[t4]};
            acc2[t4] = __builtin_amdgcn_mfma_f32_16x16x32_f16(a0.v, bw2[t4][0].v, cb, 0, 0, 0);
            acc2[t4] = __builtin_amdgcn_mfma_f32_16x16x32_f16(a1.v, bw2[t4][1].v, acc2[t4], 0, 0, 0);
        }
        #pragma unroll
        for (int r = 0; r < 4; ++r) {
            const int b = quad * 4 + r;          // valid rows 0..7 (quads 0,1)
            const float ig = sigm_n(acc2[0][r]);
            const float gg = tanh_p(acc2[2][r]);
            const float og = sigm_n(acc2[3][r]);
            const float cc = ig * gg;            // f*c0 term vanishes (c0 = 0)
            const float h2 = og * tanh_p(cc * L2E2);
            if (b < BT && jv) h2s[b * 52 + j] = h2;
        }
    }
    __syncthreads();

    // ---- FC: out[b] = h2[b] . fcW + fcb  (8 batches x 16 lanes) ----
    if (tid < BT * 16) {
        const int b = tid >> 4, l = tid & 15;
        float p = 0.f;
        for (int jj = l; jj < HH; jj += 16)
            p = __builtin_fmaf(h2s[b * 52 + jj], fcw[jj], p);
        #pragma unroll
        for (int off = 8; off > 0; off >>= 1) p += __shfl_xor(p, off, 16);
        if (l == 0) out[b0 + b] = p + fcb[0];
    }
}

extern "C" void kernel_launch(void* const* d_in, const int* in_sizes, int n_in,
                              void* d_out, int out_size, void* d_ws, size_t ws_size,
                              hipStream_t stream) {
    lstm_mfma_kernel<<<NB, 256, 0, stream>>>(
        (const float*)d_in[0],                         // x
        (const float*)d_in[1], (const float*)d_in[2],  // lstm1 Wih, Whh
        (const float*)d_in[3], (const float*)d_in[4],  // lstm1 bih, bhh
        (const float*)d_in[5],                         // lstm2 Wih
        (const float*)d_in[7], (const float*)d_in[8],  // lstm2 bih, bhh
        (const float*)d_in[9], (const float*)d_in[10], // fc W, b
        (float*)d_out);
}